// Round 3
// baseline (402.407 us; speedup 1.0000x reference)
//
#include <hip/hip_runtime.h>
#include <hip/hip_bf16.h>
#include <stdint.h>

// VQ-VAE vector quantizer for MI355X (gfx950)
// z: [32768,256] f32, codebook: [256,8192] f32
// out: z_q [8388608] f32, indices-as-f32 [32768], loss [1]
//
// Round 3: round-2 scan structure (B codebook as 4MB L2-resident bf16 image,
// global->register double-buffered, no main-loop barriers; z in LDS once)
// + round-1 PROVEN selection semantics (top-2 keys per bucket, key =
// (int)(score*256)*8192 + (8191-j), exact fp64 top-5 refine).

#define DEVINL __device__ __forceinline__

typedef float f32x4 __attribute__((ext_vector_type(4)));
typedef short short8 __attribute__((ext_vector_type(8)));

#define NROWS   32768
#define DIMS    256
#define NCODES  8192
#define KMIN    ((int)0x80000000)

// ---------------- helpers ----------------
DEVINL unsigned pkbf(float x, float y) {
  unsigned a = __float_as_uint(x); a = (a + 0x7fffu + ((a >> 16) & 1u)) >> 16;
  unsigned b = __float_as_uint(y); b = (b + 0x7fffu + ((b >> 16) & 1u)) >> 16;
  return a | (b << 16);
}

// ---------------- K1: column norms ----------------
__global__ void k_colnorm(const float* __restrict__ cb, float* __restrict__ cn) {
  __shared__ float p[256];
  int j = blockIdx.x * 32 + (threadIdx.x & 31);
  int seg = threadIdx.x >> 5;
  float s = 0.f;
  for (int i = 0; i < 32; ++i) {
    float v = cb[(size_t)(seg * 32 + i) * NCODES + j];
    s = fmaf(v, v, s);
  }
  p[threadIdx.x] = s;
  __syncthreads();
  if (threadIdx.x < 32) {
    float t = 0.f;
    for (int k = 0; k < 8; ++k) t += p[k * 32 + threadIdx.x];
    cn[j] = 0.5f * t;
  }
}

// ---------------- K2: f32 transpose cbTf[j][d] ----------------
__global__ void k_transpose(const float* __restrict__ cb, float* __restrict__ cbTf) {
  __shared__ float t[64][65];
  int j0 = blockIdx.x * 64, d0 = blockIdx.y * 64;
  int tx = threadIdx.x & 63, ty = threadIdx.x >> 6;
  #pragma unroll
  for (int i = 0; i < 16; ++i) {
    int dl = i * 4 + ty;
    t[dl][tx] = cb[(size_t)(d0 + dl) * NCODES + j0 + tx];
  }
  __syncthreads();
  #pragma unroll
  for (int i = 0; i < 16; ++i) {
    int jl = i * 4 + ty;
    cbTf[(size_t)(j0 + jl) * DIMS + d0 + tx] = t[tx][jl];
  }
}

// ---------------- K3: bf16 fragment image ----------------
// granule g (16B) = [step 128][wc 4][cf 8][lgr 4][l15 16]
//   step = tile*8+chunk; code j = tile*512 + wc*128 + cf*16 + l15
//   dims d = chunk*32 + lgr*8 .. +8
// scan: wave wc at step reads granule step*2048 + wc*512 + cf*64 + lane (linear)
__global__ void k_image(const float* __restrict__ cbTf, uint4* __restrict__ img) {
  int g = blockIdx.x * 256 + threadIdx.x;     // 0..262143
  int step = g >> 11;
  int r = g & 2047;
  int wc = r >> 9, cf = (r >> 6) & 7, lgr = (r >> 4) & 3, l15 = r & 15;
  int tile = step >> 3, chunk = step & 7;
  int j = tile * 512 + wc * 128 + cf * 16 + l15;
  int d = chunk * 32 + lgr * 8;
  const float4* s4 = (const float4*)(cbTf + (size_t)j * DIMS + d);
  float4 u = s4[0], v = s4[1];
  uint4 o;
  o.x = pkbf(u.x, u.y); o.y = pkbf(u.z, u.w);
  o.z = pkbf(v.x, v.y); o.w = pkbf(v.z, v.w);
  img[g] = o;
}

// ---------------- K4: MFMA scan, B from L2-resident image ----------------
// 256 blocks x 512 threads. Block: 128 rows x 8192 codes.
// Waves: wgr(2) x wc(4); wave-tile 64 rows x 128 codes; 16x16x32 rf4 x cf8.
// No barriers in main loop; B double-buffered in registers, 1 step ahead.
__global__ __launch_bounds__(512, 2)
void k_scan(const float* __restrict__ z, const float* __restrict__ cn,
            const short8* __restrict__ img, int2* __restrict__ cand) {
  __shared__ char smem[65536];                // z: 128 rows x 512B, XOR-swizzled
  const int t = threadIdx.x;
  const int lane = t & 63;
  const int wave = t >> 6;
  const int wgr = wave >> 2;
  const int wc  = wave & 3;
  const int l15 = lane & 15;
  const int lgr = lane >> 4;
  const int brow = blockIdx.x * 128;

  // stage z: f32 -> bf16, granule (16B) position = (col16 ^ (row&31))
  #pragma unroll
  for (int i = 0; i < 16; ++i) {
    int g = t + i * 512;
    int row = g >> 6, col = g & 63;
    float4 v = *(const float4*)(z + (size_t)(brow + row) * DIMS + col * 4);
    unsigned lo = pkbf(v.x, v.y), hi = pkbf(v.z, v.w);
    int addr = row * 512 + ((col * 8) ^ ((row & 31) << 4));
    *(uint2*)(smem + addr) = make_uint2(lo, hi);
  }

  // per row-slot top-2 packed keys (round-1 proven semantics)
  int k1[16], k2[16];
  #pragma unroll
  for (int i = 0; i < 16; ++i) { k1[i] = KMIN; k2[i] = KMIN; }

  // B prefetch: step 0 into b0
  const short8* bp = img + wc * 512 + lane;
  short8 b0[8], b1[8];
  #pragma unroll
  for (int cf = 0; cf < 8; ++cf) b0[cf] = bp[cf * 64];
  bp += 2048;

  __syncthreads();

  f32x4 acc[4][8];

  for (int tile = 0; tile < 16; ++tile) {
    // acc init: -0.5*||c||^2 (cn stays L1/L2-resident)
    #pragma unroll
    for (int cf = 0; cf < 8; ++cf) {
      float h = -cn[tile * 512 + wc * 128 + cf * 16 + l15];
      #pragma unroll
      for (int rf = 0; rf < 4; ++rf) acc[rf][cf] = f32x4{h, h, h, h};
    }
    #pragma unroll
    for (int cp = 0; cp < 4; ++cp) {
      // ---- even chunk: prefetch->b1, consume b0 ----
      #pragma unroll
      for (int cf = 0; cf < 8; ++cf) b1[cf] = bp[cf * 64];
      bp += 2048;
      {
        const int chunk = cp * 2;
        short8 a[4];
        #pragma unroll
        for (int rf = 0; rf < 4; ++rf) {
          int m = wgr * 64 + rf * 16 + l15;
          int by = ((chunk * 4 + lgr) ^ (m & 31)) << 4;
          a[rf] = *(const short8*)(smem + m * 512 + by);
        }
        #pragma unroll
        for (int rf = 0; rf < 4; ++rf)
          #pragma unroll
          for (int cf = 0; cf < 8; ++cf)
            acc[rf][cf] = __builtin_amdgcn_mfma_f32_16x16x32_bf16(a[rf], b0[cf], acc[rf][cf], 0, 0, 0);
      }
      // ---- odd chunk: prefetch->b0, consume b1 ----
      #pragma unroll
      for (int cf = 0; cf < 8; ++cf) b0[cf] = bp[cf * 64];
      bp += 2048;
      {
        const int chunk = cp * 2 + 1;
        short8 a[4];
        #pragma unroll
        for (int rf = 0; rf < 4; ++rf) {
          int m = wgr * 64 + rf * 16 + l15;
          int by = ((chunk * 4 + lgr) ^ (m & 31)) << 4;
          a[rf] = *(const short8*)(smem + m * 512 + by);
        }
        #pragma unroll
        for (int rf = 0; rf < 4; ++rf)
          #pragma unroll
          for (int cf = 0; cf < 8; ++cf)
            acc[rf][cf] = __builtin_amdgcn_mfma_f32_16x16x32_bf16(a[rf], b1[cf], acc[rf][cf], 0, 0, 0);
      }
    }
    // epilogue: fold 8 scores/row-slot into running top-2 (round-1 exact ops)
    {
      const int jinvb = 8191 - (tile * 512 + wc * 128 + l15);
      #pragma unroll
      for (int rf = 0; rf < 4; ++rf)
        #pragma unroll
        for (int cf = 0; cf < 8; ++cf) {
          int jinv = jinvb - cf * 16;
          #pragma unroll
          for (int r = 0; r < 4; ++r) {
            int si = rf * 4 + r;
            int iq = (int)(acc[rf][cf][r] * 256.0f);
            int k = iq * 8192 + jinv;
            int t1 = max(k1[si], k);
            int t2 = min(k1[si], k);
            k1[si] = t1;
            k2[si] = max(k2[si], t2);
          }
        }
    }
  }

  // write candidates: [row][64 buckets] int2
  #pragma unroll
  for (int rf = 0; rf < 4; ++rf)
    #pragma unroll
    for (int r = 0; r < 4; ++r) {
      int row = brow + wgr * 64 + rf * 16 + lgr * 4 + r;
      int si = rf * 4 + r;
      cand[(size_t)row * 64 + wc * 16 + l15] = make_int2(k1[si], k2[si]);
    }
}

// ---------------- K5: exact fp64 refine (top-5) + outputs + loss partials ----
__global__ __launch_bounds__(512)
void k_refine(const float* __restrict__ z, const float* __restrict__ cbTf,
              const int2* __restrict__ cand, float* __restrict__ zq,
              float* __restrict__ oidx, double* __restrict__ parts) {
  __shared__ double lsum[8];
  int lane = threadIdx.x & 63, wave = threadIdx.x >> 6;
  int row = blockIdx.x * 8 + wave;

  float4 z4 = ((const float4*)(z + (size_t)row * DIMS))[lane];
  int2 kp = cand[(size_t)row * 64 + lane];
  int ka = kp.x, kb = kp.y;

  double bd = 1e300; int bj = -1; float4 bc = {0.f, 0.f, 0.f, 0.f};
  for (int s = 0; s < 5; ++s) {
    int km = max(ka, kb);
    #pragma unroll
    for (int m = 1; m < 64; m <<= 1) km = max(km, __shfl_xor(km, m, 64));
    int j = 8191 - (km & 8191);
    if (ka == km) ka = KMIN; else if (kb == km) kb = KMIN;

    float4 c4 = ((const float4*)(cbTf + (size_t)j * DIMS))[lane];
    double dx = (double)z4.x - (double)c4.x;
    double dy = (double)z4.y - (double)c4.y;
    double dzv = (double)z4.z - (double)c4.z;
    double dw = (double)z4.w - (double)c4.w;
    double d = dx * dx + dy * dy + dzv * dzv + dw * dw;
    #pragma unroll
    for (int m = 1; m < 64; m <<= 1) d += __shfl_xor(d, m, 64);

    bool bt = (d < bd) || (d == bd && j < bj);   // wave-uniform
    if (bt) { bd = d; bj = j; bc = c4; }
  }

  ((float4*)(zq + (size_t)row * DIMS))[lane] = bc;
  if (lane == 0) oidx[row] = (float)bj;

  double lx = (double)bc.x - (double)z4.x;
  double ly = (double)bc.y - (double)z4.y;
  double lz = (double)bc.z - (double)z4.z;
  double lw = (double)bc.w - (double)z4.w;
  double l = lx * lx + ly * ly + lz * lz + lw * lw;
  #pragma unroll
  for (int m = 1; m < 64; m <<= 1) l += __shfl_xor(l, m, 64);
  if (lane == 0) lsum[wave] = l;
  __syncthreads();
  if (threadIdx.x == 0) {
    double s = 0;
    for (int i = 0; i < 8; ++i) s += lsum[i];
    parts[blockIdx.x] = s;
  }
}

// ---------------- K6: loss finalize ----------------
__global__ void k_finish(const double* __restrict__ parts, float* __restrict__ out) {
  __shared__ double s[256];
  double a = 0;
  for (int i = threadIdx.x; i < 4096; i += 256) a += parts[i];
  s[threadIdx.x] = a;
  __syncthreads();
  for (int w = 128; w; w >>= 1) {
    if (threadIdx.x < w) s[threadIdx.x] += s[threadIdx.x + w];
    __syncthreads();
  }
  if (threadIdx.x == 0) out[0] = (float)(1.25 * s[0] / 8388608.0);
}

// ---------------- launch ----------------
extern "C" void kernel_launch(void* const* d_in, const int* in_sizes, int n_in,
                              void* d_out, int out_size, void* d_ws, size_t ws_size,
                              hipStream_t stream) {
  const float* zin = (const float*)d_in[0];
  const float* cb  = (const float*)d_in[1];
  float* out = (float*)d_out;

  char* w = (char*)d_ws;
  float*  cn    = (float*)w;                                        // 32 KB
  float*  cbTf  = (float*)(w + 32768);                              // 8 MB
  char*   imgb  = w + 32768 + 8388608;                              // 4 MB (+32KB pad)
  int2*   cand  = (int2*)(w + 32768 + 8388608 + 4194304 + 32768);   // 16 MB
  double* parts = (double*)(w + 32768 + 8388608 + 4194304 + 32768 + 16777216); // 32 KB

  float* zq_out   = out;
  float* idx_out  = out + 8388608;
  float* loss_out = out + 8388608 + 32768;

  k_colnorm<<<dim3(256), dim3(256), 0, stream>>>(cb, cn);
  k_transpose<<<dim3(128, 4), dim3(256), 0, stream>>>(cb, cbTf);
  k_image<<<dim3(1024), dim3(256), 0, stream>>>(cbTf, (uint4*)imgb);
  k_scan<<<dim3(256), dim3(512), 0, stream>>>(zin, cn, (const short8*)imgb, cand);
  k_refine<<<dim3(4096), dim3(512), 0, stream>>>(zin, cbTf, cand, zq_out, idx_out, parts);
  k_finish<<<dim3(1), dim3(256), 0, stream>>>(parts, loss_out);
}